// Round 5
// baseline (413.501 us; speedup 1.0000x reference)
//
#include <hip/hip_runtime.h>
#include <hip/hip_bf16.h>
#include <cstdint>

typedef unsigned short U16;
typedef float f32x4 __attribute__((ext_vector_type(4)));
typedef __bf16 bf16x8 __attribute__((ext_vector_type(8)));

#define DEVINL __device__ __forceinline__

DEVINL U16 f2bf(float f) {
    unsigned u = __float_as_uint(f);
    return (U16)((u + 0x7FFFu + ((u >> 16) & 1u)) >> 16);  // RN-even
}
DEVINL float bf2f(U16 s) { return __uint_as_float(((unsigned)s) << 16); }

DEVINL void gld16(const void* g, void* l) {
    __builtin_amdgcn_global_load_lds(
        (const __attribute__((address_space(1))) void*)g,
        (__attribute__((address_space(3))) void*)l, 16, 0, 0);
}

#define MFMA_BF16 __builtin_amdgcn_mfma_f32_16x16x32_bf16

// ---------------- weight transpose + cast: wt[n][k] = (bf16) w[k][n] ----------------
__global__ __launch_bounds__(256) void tcast_kernel(const float* __restrict__ w,
                                                    U16* __restrict__ wt, int K, int N) {
    __shared__ float tile[32][33];
    int n0 = blockIdx.x * 32, k0 = blockIdx.y * 32;
    int tx = threadIdx.x, ty = threadIdx.y;  // 32 x 8
#pragma unroll
    for (int i = 0; i < 32; i += 8) tile[ty + i][tx] = w[(size_t)(k0 + ty + i) * N + (n0 + tx)];
    __syncthreads();
#pragma unroll
    for (int i = 0; i < 32; i += 8) wt[(size_t)(n0 + ty + i) * K + (k0 + tx)] = f2bf(tile[tx][ty + i]);
}

// ---------------- LayerNorm over 512, one wave per row, bf16 out ----------------
__global__ __launch_bounds__(256) void ln_kernel(const float* __restrict__ x,
                                                 const float* __restrict__ g,
                                                 const float* __restrict__ b,
                                                 U16* __restrict__ out) {
    int lane = threadIdx.x & 63;
    size_t row = (size_t)blockIdx.x * 4 + (threadIdx.x >> 6);
    const float4* xr = (const float4*)(x + row * 512);
    float4 v0 = xr[lane], v1 = xr[lane + 64];
    float s = (v0.x + v0.y) + (v0.z + v0.w) + (v1.x + v1.y) + (v1.z + v1.w);
    float sq = (v0.x * v0.x + v0.y * v0.y + v0.z * v0.z + v0.w * v0.w) +
               (v1.x * v1.x + v1.y * v1.y + v1.z * v1.z + v1.w * v1.w);
#pragma unroll
    for (int m = 1; m < 64; m <<= 1) { s += __shfl_xor(s, m); sq += __shfl_xor(sq, m); }
    float mu = s * (1.f / 512.f);
    float var = sq * (1.f / 512.f) - mu * mu;
    float rs = rsqrtf(var + 1e-5f);
    const float4* g4 = (const float4*)g;
    const float4* b4 = (const float4*)b;
    float4 gv = g4[lane], bv = b4[lane];
    ushort4 o;
    o.x = f2bf((v0.x - mu) * rs * gv.x + bv.x);
    o.y = f2bf((v0.y - mu) * rs * gv.y + bv.y);
    o.z = f2bf((v0.z - mu) * rs * gv.z + bv.z);
    o.w = f2bf((v0.w - mu) * rs * gv.w + bv.w);
    ((ushort4*)(out + row * 512))[lane] = o;
    gv = g4[lane + 64]; bv = b4[lane + 64];
    o.x = f2bf((v1.x - mu) * rs * gv.x + bv.x);
    o.y = f2bf((v1.y - mu) * rs * gv.y + bv.y);
    o.z = f2bf((v1.z - mu) * rs * gv.z + bv.z);
    o.w = f2bf((v1.w - mu) * rs * gv.w + bv.w);
    ((ushort4*)(out + row * 512))[lane + 64] = o;
}

// ---------------- 256x256 ring-4 pipelined GEMM ----------------
// C[M,N] = A[M,K](bf16) * Bt[N,K](bf16)^T + bias (+gelu / +resid)
// 512 threads = 8 waves (2M x 4N), wave tile 128x64, BK=32.
// LDS: ring of 4 one-K-tile buffers (32KB each = A[256][32] + B[256][32]), 128KB total.
// Iter t: stage tile t+2 (4 gld16/thread) ; s_waitcnt vmcnt(8) -> tile t landed,
// tiles t+1,t+2 stay in flight (64KB) ; one s_barrier ; 12 ds_read_b128 + 32 MFMA.
// Never drains vmcnt to 0 until the last two tiles.
// Swizzle: phys 16B chunk = logical ^ (row&3) (pre-swizzled global source, swizzled read).
// EPI 0: bf16 out (bias); EPI 1: fp32 out (bias+resid); EPI 2: bf16 out (bias+gelu)
template <int EPI>
__global__ __launch_bounds__(512, 2) void gemm256(const U16* __restrict__ A,
                                                  const U16* __restrict__ Bt,
                                                  const float* __restrict__ bias,
                                                  const float* __restrict__ resid,
                                                  U16* __restrict__ outb,
                                                  float* __restrict__ outf,
                                                  int M, int N, int K, int gridN) {
    // buffer b at b*16384 U16; within buffer:
    //   A rows [0,128) at +0, A rows [128,256) at +4096,
    //   B rows [0,128) at +8192, B rows [128,256) at +12288
    // row r, phys chunk c (16B): seg(r>>7)*4096 + (r&127)*32 + c*8
    __shared__ __align__(16) U16 smem[65536];

    const int tid = threadIdx.x;
    const int lane = tid & 63, wv = tid >> 6;
    const int lo = lane & 15, hi = lane >> 4;
    const int wm = wv >> 2, wn = wv & 3;  // 2 x 4 wave grid, wave tile 128x64

    const int nwg = gridDim.x, bid = blockIdx.x;
    const int swz = (bid & 7) * (nwg >> 3) + (bid >> 3);
    const int bn = swz % gridN, bm = swz / gridN;

    // staging: thread -> row-in-segment (tid>>2), phys chunk (tid&3);
    // logical chunk = phys ^ (row&3) -> pre-swizzled global source column
    const int sr = tid >> 2;                     // 0..127
    const int lc = (tid & 3) ^ (sr & 3);
    const U16* gA0 = A + (size_t)(bm * 256 + sr) * K + lc * 8;
    const U16* gB0 = Bt + (size_t)(bn * 256 + sr) * K + lc * 8;

#define STAGE(t2)                                                     \
    do {                                                              \
        const int _b = ((t2) & 3) * 16384;                            \
        const U16* _ga = gA0 + (size_t)(t2) * 32;                     \
        const U16* _gb = gB0 + (size_t)(t2) * 32;                     \
        U16* _la = smem + _b + tid * 8;                               \
        U16* _lb = smem + _b + 8192 + tid * 8;                        \
        gld16(_ga, _la);                                              \
        gld16(_ga + (size_t)128 * K, _la + 4096);                     \
        gld16(_gb, _lb);                                              \
        gld16(_gb + (size_t)128 * K, _lb + 4096);                     \
    } while (0)

    const int ck = (hi ^ (lo & 3)) << 3;  // swizzled 16B-chunk offset (U16 units)

    f32x4 acc[8][4] = {};

    const int nt = K >> 5;
    // prologue: stage tiles 0 and 1
    STAGE(0);
    STAGE(1);

    for (int t = 0; t < nt; ++t) {
        if (t + 2 < nt) {
            STAGE(t + 2);
            asm volatile("s_waitcnt vmcnt(8)" ::: "memory");
        } else if (t + 1 < nt) {
            asm volatile("s_waitcnt vmcnt(4)" ::: "memory");
        } else {
            asm volatile("s_waitcnt vmcnt(0)" ::: "memory");
        }
        asm volatile("s_barrier" ::: "memory");

        const int cb = (t & 3) * 16384;
        const U16* Abuf = smem + cb + wm * 4096;
        const U16* Bbuf = smem + cb + 8192 + (wn >> 1) * 4096;
        const int brow = (wn & 1) * 64;

        bf16x8 af[8], bg[4];
#pragma unroll
        for (int j = 0; j < 4; ++j)
            bg[j] = *(const bf16x8*)(Bbuf + (brow + j * 16 + lo) * 32 + ck);
#pragma unroll
        for (int i = 0; i < 8; ++i)
            af[i] = *(const bf16x8*)(Abuf + (i * 16 + lo) * 32 + ck);

        __builtin_amdgcn_s_setprio(1);
#pragma unroll
        for (int i = 0; i < 8; ++i)
#pragma unroll
            for (int j = 0; j < 4; ++j)
                acc[i][j] = MFMA_BF16(af[i], bg[j], acc[i][j], 0, 0, 0);
        __builtin_amdgcn_s_setprio(0);
    }

    // ---- epilogue: direct stores ----
    const int row0 = bm * 256 + wm * 128 + hi * 4;
    const int col0 = bn * 256 + wn * 64 + lo;
    float bc[4];
#pragma unroll
    for (int j = 0; j < 4; ++j) bc[j] = bias[col0 + j * 16];

    if (EPI == 1) {
#pragma unroll
        for (int i = 0; i < 8; ++i)
#pragma unroll
            for (int r = 0; r < 4; ++r) {
                const size_t rowb = (size_t)(row0 + i * 16 + r) * N;
#pragma unroll
                for (int j = 0; j < 4; ++j) {
                    const size_t idx = rowb + col0 + j * 16;
                    outf[idx] = acc[i][j][r] + bc[j] + resid[idx];
                }
            }
    } else {
#pragma unroll
        for (int i = 0; i < 8; ++i)
#pragma unroll
            for (int j = 0; j < 4; ++j)
#pragma unroll
                for (int r = 0; r < 4; ++r) {
                    float v = acc[i][j][r] + bc[j];
                    if (EPI == 2) v = 0.5f * v * (1.f + erff(v * 0.70710678118654752f));
                    outb[(size_t)(row0 + i * 16 + r) * N + col0 + j * 16] = f2bf(v);
                }
    }
#undef STAGE
}

// ---------------- windowed attention: one block per (window, head) ----------------
// qkv: [32768][1536] bf16, layout [3][8][64] in last dim. o: [32768][512] bf16.
__global__ __launch_bounds__(256) void attn_kernel(const U16* __restrict__ qkv,
                                                   U16* __restrict__ o) {
    const int blk = blockIdx.x;
    const int w = blk >> 3, h = blk & 7;
    const int tid = threadIdx.x;
    const int lane = tid & 63, wv = tid >> 6;
    const int lo = lane & 15, hi = lane >> 4;

    __shared__ __align__(16) U16 Qs[64][72];
    __shared__ __align__(16) U16 Ks[64][72];
    __shared__ __align__(16) U16 Vt[64][72];  // V transposed: Vt[d][j]
    __shared__ __align__(16) U16 Ps[4][16][72];

    {
        const int r = tid >> 2;
        const int c0 = (tid & 3) << 4;
        const U16* p = qkv + (size_t)(w * 64 + r) * 1536 + h * 64 + c0;
        *(bf16x8*)&Ks[r][c0] = *(const bf16x8*)(p + 512);
        *(bf16x8*)&Ks[r][c0 + 8] = *(const bf16x8*)(p + 520);
        const U16* pv = p + 1024;
#pragma unroll
        for (int i = 0; i < 16; i++) Vt[c0 + i][r] = pv[i];
#pragma unroll
        for (int i = 0; i < 16; i++) Qs[r][c0 + i] = f2bf(bf2f(p[i]) * 0.125f);
    }
    __syncthreads();

    const int rb = wv * 16;  // this wave's 16 score rows
    f32x4 s[4] = {};
#pragma unroll
    for (int dc = 0; dc < 64; dc += 32) {
        bf16x8 a = *(const bf16x8*)&Qs[rb + lo][dc + hi * 8];
#pragma unroll
        for (int jb = 0; jb < 4; jb++) {
            bf16x8 bfr = *(const bf16x8*)&Ks[jb * 16 + lo][dc + hi * 8];
            s[jb] = MFMA_BF16(a, bfr, s[jb], 0, 0, 0);
        }
    }
#pragma unroll
    for (int r = 0; r < 4; r++) {
        float m = fmaxf(fmaxf(s[0][r], s[1][r]), fmaxf(s[2][r], s[3][r]));
#pragma unroll
        for (int msk = 1; msk < 16; msk <<= 1) m = fmaxf(m, __shfl_xor(m, msk));
        float e[4], sum = 0.f;
#pragma unroll
        for (int jb = 0; jb < 4; jb++) { e[jb] = expf(s[jb][r] - m); sum += e[jb]; }
#pragma unroll
        for (int msk = 1; msk < 16; msk <<= 1) sum += __shfl_xor(sum, msk);
        float inv = 1.f / sum;
#pragma unroll
        for (int jb = 0; jb < 4; jb++) Ps[wv][hi * 4 + r][jb * 16 + lo] = f2bf(e[jb] * inv);
    }
    __syncthreads();

    f32x4 oa[4] = {};
#pragma unroll
    for (int jc = 0; jc < 64; jc += 32) {
        bf16x8 a = *(const bf16x8*)&Ps[wv][lo][jc + hi * 8];
#pragma unroll
        for (int db = 0; db < 4; db++) {
            bf16x8 bfr = *(const bf16x8*)&Vt[db * 16 + lo][jc + hi * 8];
            oa[db] = MFMA_BF16(a, bfr, oa[db], 0, 0, 0);
        }
    }
#pragma unroll
    for (int db = 0; db < 4; db++)
#pragma unroll
        for (int r = 0; r < 4; r++)
            o[(size_t)(w * 64 + rb + hi * 4 + r) * 512 + h * 64 + db * 16 + lo] = f2bf(oa[db][r]);
}

// ---------------- launch ----------------
extern "C" void kernel_launch(void* const* d_in, const int* in_sizes, int n_in,
                              void* d_out, int out_size, void* d_ws, size_t ws_size,
                              hipStream_t stream) {
    const float* x = (const float*)d_in[0];
    const float* ln1_g = (const float*)d_in[1];
    const float* ln1_b = (const float*)d_in[2];
    const float* qkv_w = (const float*)d_in[3];
    const float* qkv_b = (const float*)d_in[4];
    const float* proj_w = (const float*)d_in[5];
    const float* proj_b = (const float*)d_in[6];
    const float* ln2_g = (const float*)d_in[7];
    const float* ln2_b = (const float*)d_in[8];
    const float* fc1_w = (const float*)d_in[9];
    const float* fc1_b = (const float*)d_in[10];
    const float* fc2_w = (const float*)d_in[11];
    const float* fc2_b = (const float*)d_in[12];
    float* out = (float*)d_out;

    char* ws = (char*)d_ws;
    U16* hbuf = (U16*)ws;                               // 32768*512 bf16
    U16* big = (U16*)(ws + 33554432);                   // 32768*2048 bf16 max
    U16* wt_qkv = (U16*)(ws + 33554432 + 134217728);    // 1536*512
    U16* wt_proj = wt_qkv + 1536 * 512;                 // 512*512
    U16* wt_fc1 = wt_proj + 512 * 512;                  // 2048*512
    U16* wt_fc2 = wt_fc1 + 2048 * 512;                  // 512*2048

    dim3 tb(32, 8);
    tcast_kernel<<<dim3(1536 / 32, 512 / 32), tb, 0, stream>>>(qkv_w, wt_qkv, 512, 1536);
    tcast_kernel<<<dim3(512 / 32, 512 / 32), tb, 0, stream>>>(proj_w, wt_proj, 512, 512);
    tcast_kernel<<<dim3(2048 / 32, 512 / 32), tb, 0, stream>>>(fc1_w, wt_fc1, 512, 2048);
    tcast_kernel<<<dim3(512 / 32, 2048 / 32), tb, 0, stream>>>(fc2_w, wt_fc2, 2048, 512);

    ln_kernel<<<8192, 256, 0, stream>>>(x, ln1_g, ln1_b, hbuf);
    gemm256<0><<<768, 512, 0, stream>>>(hbuf, wt_qkv, qkv_b, nullptr, big, nullptr, 32768, 1536, 512, 6);
    attn_kernel<<<4096, 256, 0, stream>>>(big, hbuf);
    gemm256<1><<<256, 512, 0, stream>>>(hbuf, wt_proj, proj_b, x, nullptr, out, 32768, 512, 512, 2);
    ln_kernel<<<8192, 256, 0, stream>>>(out, ln2_g, ln2_b, hbuf);
    gemm256<2><<<1024, 512, 0, stream>>>(hbuf, wt_fc1, fc1_b, nullptr, big, nullptr, 32768, 2048, 512, 8);
    gemm256<1><<<256, 512, 0, stream>>>(big, wt_fc2, fc2_b, out, nullptr, out, 32768, 512, 2048, 2);
}

// Round 6
// 399.104 us; speedup vs baseline: 1.0361x; 1.0361x over previous
//
#include <hip/hip_runtime.h>
#include <hip/hip_bf16.h>
#include <cstdint>

typedef unsigned short U16;
typedef float f32x4 __attribute__((ext_vector_type(4)));
typedef __bf16 bf16x8 __attribute__((ext_vector_type(8)));

#define DEVINL __device__ __forceinline__

DEVINL U16 f2bf(float f) {
    unsigned u = __float_as_uint(f);
    return (U16)((u + 0x7FFFu + ((u >> 16) & 1u)) >> 16);  // RN-even
}
DEVINL float bf2f(U16 s) { return __uint_as_float(((unsigned)s) << 16); }

DEVINL void gld16(const void* g, void* l) {
    __builtin_amdgcn_global_load_lds(
        (const __attribute__((address_space(1))) void*)g,
        (__attribute__((address_space(3))) void*)l, 16, 0, 0);
}

#define MFMA_BF16 __builtin_amdgcn_mfma_f32_16x16x32_bf16

// ---------------- weight transpose + cast: wt[n][k] = (bf16) w[k][n] ----------------
__global__ __launch_bounds__(256) void tcast_kernel(const float* __restrict__ w,
                                                    U16* __restrict__ wt, int K, int N) {
    __shared__ float tile[32][33];
    int n0 = blockIdx.x * 32, k0 = blockIdx.y * 32;
    int tx = threadIdx.x, ty = threadIdx.y;  // 32 x 8
#pragma unroll
    for (int i = 0; i < 32; i += 8) tile[ty + i][tx] = w[(size_t)(k0 + ty + i) * N + (n0 + tx)];
    __syncthreads();
#pragma unroll
    for (int i = 0; i < 32; i += 8) wt[(size_t)(n0 + ty + i) * K + (k0 + tx)] = f2bf(tile[tx][ty + i]);
}

// ---------------- LayerNorm over 512, one wave per row, bf16 out ----------------
__global__ __launch_bounds__(256) void ln_kernel(const float* __restrict__ x,
                                                 const float* __restrict__ g,
                                                 const float* __restrict__ b,
                                                 U16* __restrict__ out) {
    int lane = threadIdx.x & 63;
    size_t row = (size_t)blockIdx.x * 4 + (threadIdx.x >> 6);
    const float4* xr = (const float4*)(x + row * 512);
    float4 v0 = xr[lane], v1 = xr[lane + 64];
    float s = (v0.x + v0.y) + (v0.z + v0.w) + (v1.x + v1.y) + (v1.z + v1.w);
    float sq = (v0.x * v0.x + v0.y * v0.y + v0.z * v0.z + v0.w * v0.w) +
               (v1.x * v1.x + v1.y * v1.y + v1.z * v1.z + v1.w * v1.w);
#pragma unroll
    for (int m = 1; m < 64; m <<= 1) { s += __shfl_xor(s, m); sq += __shfl_xor(sq, m); }
    float mu = s * (1.f / 512.f);
    float var = sq * (1.f / 512.f) - mu * mu;
    float rs = rsqrtf(var + 1e-5f);
    const float4* g4 = (const float4*)g;
    const float4* b4 = (const float4*)b;
    float4 gv = g4[lane], bv = b4[lane];
    ushort4 o;
    o.x = f2bf((v0.x - mu) * rs * gv.x + bv.x);
    o.y = f2bf((v0.y - mu) * rs * gv.y + bv.y);
    o.z = f2bf((v0.z - mu) * rs * gv.z + bv.z);
    o.w = f2bf((v0.w - mu) * rs * gv.w + bv.w);
    ((ushort4*)(out + row * 512))[lane] = o;
    gv = g4[lane + 64]; bv = b4[lane + 64];
    o.x = f2bf((v1.x - mu) * rs * gv.x + bv.x);
    o.y = f2bf((v1.y - mu) * rs * gv.y + bv.y);
    o.z = f2bf((v1.z - mu) * rs * gv.z + bv.z);
    o.w = f2bf((v1.w - mu) * rs * gv.w + bv.w);
    ((ushort4*)(out + row * 512))[lane + 64] = o;
}

// ---------------- 256x256 8-phase lockstep GEMM (m201-style) ----------------
// C[M,N] = A[M,K](bf16) * Bt[N,K](bf16)^T + bias (+gelu / +resid)
// 512 threads = 8 waves (2M x 4N), wave tile 128x64, BK=64, 128KB double-buffered LDS.
// Per K-tile: top vmcnt(0)+publish barrier (drains exactly this tile's 8 loads, issued
// >=2 phases earlier; prefetches never drain mid-tile), then 4 phases:
//   { ds_read subtile ; stage half-tiles of next K-tile (A in ph1, B in ph2) ;
//     s_barrier ; lgkmcnt(0) ; setprio(1) ; 16 MFMA quadrant ; setprio(0) ; s_barrier }
// Swizzle (round-4, measured 0 conflicts): phys 16B chunk = logical ^ (row&7),
// via pre-swizzled global source + XOR'd ds_read chunk offset.
// EPI 0: bf16 out (bias); EPI 1: fp32 out (bias+resid); EPI 2: bf16 out (bias+gelu)
template <int EPI>
__global__ __launch_bounds__(512, 1) void gemm256(const U16* __restrict__ A,
                                                  const U16* __restrict__ Bt,
                                                  const float* __restrict__ bias,
                                                  const float* __restrict__ resid,
                                                  U16* __restrict__ outb,
                                                  float* __restrict__ outf,
                                                  int M, int N, int K, int gridN) {
    // buf b at b*32768 U16: A[256][64] at +0, B[256][64] at +16384
    __shared__ __align__(16) U16 smem[65536];

    const int tid = threadIdx.x;
    const int lane = tid & 63, wv = tid >> 6;
    const int lo = lane & 15, hi = lane >> 4;
    const int wm = wv >> 2, wn = wv & 3;  // 2 x 4 wave grid, wave tile 128x64

    const int nwg = gridDim.x, bid = blockIdx.x;
    const int swz = (bid & 7) * (nwg >> 3) + (bid >> 3);
    const int bn = swz % gridN, bm = swz / gridN;

    // staging: row sr = tid>>3 (0..63), phys chunk tid&7; logical = phys ^ (row&7)
    const int sr = tid >> 3;
    const int clog = (tid & 7) ^ (sr & 7);
    const U16* gA0 = A + (size_t)(bm * 256 + sr) * K + clog * 8;
    const U16* gB0 = Bt + (size_t)(bn * 256 + sr) * K + clog * 8;

// stage half h (rows [h*128, h*128+128)) of A (matoff 0) or B (matoff 16384), tile t1
#define STAGE_H(g0, matoff, h, t1)                                              \
    do {                                                                        \
        U16* _l = smem + (((t1) & 1) << 15) + (matoff) + (h) * 8192 + tid * 8;  \
        const U16* _g = (g0) + (size_t)(t1) * 64 + (size_t)((h) * 128) * K;     \
        gld16(_g, _l);                                                          \
        gld16(_g + (size_t)64 * K, _l + 4096);                                  \
    } while (0)

    // swizzled ds_read chunk offsets (U16 units) for kk=0,1
    const int ck0 = ((hi) ^ (lo & 7)) << 3;
    const int ck1 = ((4 | hi) ^ (lo & 7)) << 3;

    f32x4 acc[8][4] = {};

    const int nt = K >> 6;
    // prologue: stage tile 0 fully (8 gld16/thread)
    STAGE_H(gA0, 0, 0, 0);
    STAGE_H(gA0, 0, 1, 0);
    STAGE_H(gB0, 16384, 0, 0);
    STAGE_H(gB0, 16384, 1, 0);

    for (int t = 0; t < nt; ++t) {
        const int cb = (t & 1) << 15;
        const bool pf = (t + 1 < nt);
        // tile-top: exactly this tile's 8 loads are outstanding -> counted-exact drain
        asm volatile("s_waitcnt vmcnt(0)" ::: "memory");
        __builtin_amdgcn_s_barrier();

        const U16* Ab = smem + cb + (wm * 128 + lo) * 64;
        const U16* Bb = smem + cb + 16384 + (wn * 64 + lo) * 64;

        bf16x8 af[4][2], bg[4][2];

        // ---- phase 1: Q00 (acc[0..3][0..1]) ; stage next-tile A halves ----
#pragma unroll
        for (int i = 0; i < 4; ++i) {
            af[i][0] = *(const bf16x8*)(Ab + i * 1024 + ck0);
            af[i][1] = *(const bf16x8*)(Ab + i * 1024 + ck1);
        }
#pragma unroll
        for (int j = 0; j < 2; ++j) {
            bg[j][0] = *(const bf16x8*)(Bb + j * 1024 + ck0);
            bg[j][1] = *(const bf16x8*)(Bb + j * 1024 + ck1);
        }
        if (pf) {
            STAGE_H(gA0, 0, 0, t + 1);
            STAGE_H(gA0, 0, 1, t + 1);
        }
        __builtin_amdgcn_s_barrier();
        asm volatile("s_waitcnt lgkmcnt(0)" ::: "memory");
        __builtin_amdgcn_s_setprio(1);
#pragma unroll
        for (int i = 0; i < 4; ++i)
#pragma unroll
            for (int j = 0; j < 2; ++j) {
                acc[i][j] = MFMA_BF16(af[i][0], bg[j][0], acc[i][j], 0, 0, 0);
                acc[i][j] = MFMA_BF16(af[i][1], bg[j][1], acc[i][j], 0, 0, 0);
            }
        __builtin_amdgcn_s_setprio(0);
        __builtin_amdgcn_s_barrier();

        // ---- phase 2: Q01 (acc[0..3][2..3]) ; stage next-tile B halves ----
#pragma unroll
        for (int j = 2; j < 4; ++j) {
            bg[j][0] = *(const bf16x8*)(Bb + j * 1024 + ck0);
            bg[j][1] = *(const bf16x8*)(Bb + j * 1024 + ck1);
        }
        if (pf) {
            STAGE_H(gB0, 16384, 0, t + 1);
            STAGE_H(gB0, 16384, 1, t + 1);
        }
        __builtin_amdgcn_s_barrier();
        asm volatile("s_waitcnt lgkmcnt(0)" ::: "memory");
        __builtin_amdgcn_s_setprio(1);
#pragma unroll
        for (int i = 0; i < 4; ++i)
#pragma unroll
            for (int j = 2; j < 4; ++j) {
                acc[i][j] = MFMA_BF16(af[i][0], bg[j][0], acc[i][j], 0, 0, 0);
                acc[i][j] = MFMA_BF16(af[i][1], bg[j][1], acc[i][j], 0, 0, 0);
            }
        __builtin_amdgcn_s_setprio(0);
        __builtin_amdgcn_s_barrier();

        // ---- phase 3: Q10 (acc[4..7][0..1]) ; reload af with rows 64..127 ----
#pragma unroll
        for (int i = 0; i < 4; ++i) {
            af[i][0] = *(const bf16x8*)(Ab + (i + 4) * 1024 + ck0);
            af[i][1] = *(const bf16x8*)(Ab + (i + 4) * 1024 + ck1);
        }
        __builtin_amdgcn_s_barrier();
        asm volatile("s_waitcnt lgkmcnt(0)" ::: "memory");
        __builtin_amdgcn_s_setprio(1);
#pragma unroll
        for (int i = 0; i < 4; ++i)
#pragma unroll
            for (int j = 0; j < 2; ++j) {
                acc[4 + i][j] = MFMA_BF16(af[i][0], bg[j][0], acc[4 + i][j], 0, 0, 0);
                acc[4 + i][j] = MFMA_BF16(af[i][1], bg[j][1], acc[4 + i][j], 0, 0, 0);
            }
        __builtin_amdgcn_s_setprio(0);
        __builtin_amdgcn_s_barrier();

        // ---- phase 4: Q11 (acc[4..7][2..3]) ; all regs resident ----
        __builtin_amdgcn_s_setprio(1);
#pragma unroll
        for (int i = 0; i < 4; ++i)
#pragma unroll
            for (int j = 2; j < 4; ++j) {
                acc[4 + i][j] = MFMA_BF16(af[i][0], bg[j][0], acc[4 + i][j], 0, 0, 0);
                acc[4 + i][j] = MFMA_BF16(af[i][1], bg[j][1], acc[4 + i][j], 0, 0, 0);
            }
        __builtin_amdgcn_s_setprio(0);
        // next tile-top barrier doubles as the read-complete fence for this buffer
    }

    // ---- epilogue: direct stores ----
    const int row0 = bm * 256 + wm * 128 + hi * 4;
    const int col0 = bn * 256 + wn * 64 + lo;
    float bc[4];
#pragma unroll
    for (int j = 0; j < 4; ++j) bc[j] = bias[col0 + j * 16];

    if (EPI == 1) {
#pragma unroll
        for (int i = 0; i < 8; ++i)
#pragma unroll
            for (int r = 0; r < 4; ++r) {
                const size_t rowb = (size_t)(row0 + i * 16 + r) * N;
#pragma unroll
                for (int j = 0; j < 4; ++j) {
                    const size_t idx = rowb + col0 + j * 16;
                    outf[idx] = acc[i][j][r] + bc[j] + resid[idx];
                }
            }
    } else {
#pragma unroll
        for (int i = 0; i < 8; ++i)
#pragma unroll
            for (int j = 0; j < 4; ++j)
#pragma unroll
                for (int r = 0; r < 4; ++r) {
                    float v = acc[i][j][r] + bc[j];
                    if (EPI == 2) v = 0.5f * v * (1.f + erff(v * 0.70710678118654752f));
                    outb[(size_t)(row0 + i * 16 + r) * N + col0 + j * 16] = f2bf(v);
                }
    }
#undef STAGE_H
}

// ---------------- windowed attention: one block per (window, head) ----------------
// qkv: [32768][1536] bf16, layout [3][8][64] in last dim. o: [32768][512] bf16.
__global__ __launch_bounds__(256) void attn_kernel(const U16* __restrict__ qkv,
                                                   U16* __restrict__ o) {
    const int blk = blockIdx.x;
    const int w = blk >> 3, h = blk & 7;
    const int tid = threadIdx.x;
    const int lane = tid & 63, wv = tid >> 6;
    const int lo = lane & 15, hi = lane >> 4;

    __shared__ __align__(16) U16 Qs[64][72];
    __shared__ __align__(16) U16 Ks[64][72];
    __shared__ __align__(16) U16 Vt[64][72];  // V transposed: Vt[d][j]
    __shared__ __align__(16) U16 Ps[4][16][72];

    {
        const int r = tid >> 2;
        const int c0 = (tid & 3) << 4;
        const U16* p = qkv + (size_t)(w * 64 + r) * 1536 + h * 64 + c0;
        *(bf16x8*)&Ks[r][c0] = *(const bf16x8*)(p + 512);
        *(bf16x8*)&Ks[r][c0 + 8] = *(const bf16x8*)(p + 520);
        const U16* pv = p + 1024;
#pragma unroll
        for (int i = 0; i < 16; i++) Vt[c0 + i][r] = pv[i];
#pragma unroll
        for (int i = 0; i < 16; i++) Qs[r][c0 + i] = f2bf(bf2f(p[i]) * 0.125f);
    }
    __syncthreads();

    const int rb = wv * 16;  // this wave's 16 score rows
    f32x4 s[4] = {};
#pragma unroll
    for (int dc = 0; dc < 64; dc += 32) {
        bf16x8 a = *(const bf16x8*)&Qs[rb + lo][dc + hi * 8];
#pragma unroll
        for (int jb = 0; jb < 4; jb++) {
            bf16x8 bfr = *(const bf16x8*)&Ks[jb * 16 + lo][dc + hi * 8];
            s[jb] = MFMA_BF16(a, bfr, s[jb], 0, 0, 0);
        }
    }
#pragma unroll
    for (int r = 0; r < 4; r++) {
        float m = fmaxf(fmaxf(s[0][r], s[1][r]), fmaxf(s[2][r], s[3][r]));
#pragma unroll
        for (int msk = 1; msk < 16; msk <<= 1) m = fmaxf(m, __shfl_xor(m, msk));
        float e[4], sum = 0.f;
#pragma unroll
        for (int jb = 0; jb < 4; jb++) { e[jb] = expf(s[jb][r] - m); sum += e[jb]; }
#pragma unroll
        for (int msk = 1; msk < 16; msk <<= 1) sum += __shfl_xor(sum, msk);
        float inv = 1.f / sum;
#pragma unroll
        for (int jb = 0; jb < 4; jb++) Ps[wv][hi * 4 + r][jb * 16 + lo] = f2bf(e[jb] * inv);
    }
    __syncthreads();

    f32x4 oa[4] = {};
#pragma unroll
    for (int jc = 0; jc < 64; jc += 32) {
        bf16x8 a = *(const bf16x8*)&Ps[wv][lo][jc + hi * 8];
#pragma unroll
        for (int db = 0; db < 4; db++) {
            bf16x8 bfr = *(const bf16x8*)&Vt[db * 16 + lo][jc + hi * 8];
            oa[db] = MFMA_BF16(a, bfr, oa[db], 0, 0, 0);
        }
    }
#pragma unroll
    for (int db = 0; db < 4; db++)
#pragma unroll
        for (int r = 0; r < 4; r++)
            o[(size_t)(w * 64 + rb + hi * 4 + r) * 512 + h * 64 + db * 16 + lo] = f2bf(oa[db][r]);
}

// ---------------- launch ----------------
extern "C" void kernel_launch(void* const* d_in, const int* in_sizes, int n_in,
                              void* d_out, int out_size, void* d_ws, size_t ws_size,
                              hipStream_t stream) {
    const float* x = (const float*)d_in[0];
    const float* ln1_g = (const float*)d_in[1];
    const float* ln1_b = (const float*)d_in[2];
    const float* qkv_w = (const float*)d_in[3];
    const float* qkv_b = (const float*)d_in[4];
    const float* proj_w = (const float*)d_in[5];
    const float* proj_b = (const float*)d_in[6];
    const float* ln2_g = (const float*)d_in[7];
    const float* ln2_b = (const float*)d_in[8];
    const float* fc1_w = (const float*)d_in[9];
    const float* fc1_b = (const float*)d_in[10];
    const float* fc2_w = (const float*)d_in[11];
    const float* fc2_b = (const float*)d_in[12];
    float* out = (float*)d_out;

    char* ws = (char*)d_ws;
    U16* hbuf = (U16*)ws;                               // 32768*512 bf16
    U16* big = (U16*)(ws + 33554432);                   // 32768*2048 bf16 max
    U16* wt_qkv = (U16*)(ws + 33554432 + 134217728);    // 1536*512
    U16* wt_proj = wt_qkv + 1536 * 512;                 // 512*512
    U16* wt_fc1 = wt_proj + 512 * 512;                  // 2048*512
    U16* wt_fc2 = wt_fc1 + 2048 * 512;                  // 512*2048

    dim3 tb(32, 8);
    tcast_kernel<<<dim3(1536 / 32, 512 / 32), tb, 0, stream>>>(qkv_w, wt_qkv, 512, 1536);
    tcast_kernel<<<dim3(512 / 32, 512 / 32), tb, 0, stream>>>(proj_w, wt_proj, 512, 512);
    tcast_kernel<<<dim3(2048 / 32, 512 / 32), tb, 0, stream>>>(fc1_w, wt_fc1, 512, 2048);
    tcast_kernel<<<dim3(512 / 32, 2048 / 32), tb, 0, stream>>>(fc2_w, wt_fc2, 2048, 512);

    ln_kernel<<<8192, 256, 0, stream>>>(x, ln1_g, ln1_b, hbuf);
    gemm256<0><<<768, 512, 0, stream>>>(hbuf, wt_qkv, qkv_b, nullptr, big, nullptr, 32768, 1536, 512, 6);
    attn_kernel<<<4096, 256, 0, stream>>>(big, hbuf);
    gemm256<1><<<256, 512, 0, stream>>>(hbuf, wt_proj, proj_b, x, nullptr, out, 32768, 512, 512, 2);
    ln_kernel<<<8192, 256, 0, stream>>>(out, ln2_g, ln2_b, hbuf);
    gemm256<2><<<1024, 512, 0, stream>>>(hbuf, wt_fc1, fc1_b, nullptr, big, nullptr, 32768, 2048, 512, 8);
    gemm256<1><<<256, 512, 0, stream>>>(big, wt_fc2, fc2_b, out, nullptr, out, 32768, 512, 2048, 2);
}

// Round 7
// 388.997 us; speedup vs baseline: 1.0630x; 1.0260x over previous
//
#include <hip/hip_runtime.h>
#include <hip/hip_bf16.h>
#include <cstdint>

typedef unsigned short U16;
typedef float f32x4 __attribute__((ext_vector_type(4)));
typedef __bf16 bf16x8 __attribute__((ext_vector_type(8)));

#define DEVINL __device__ __forceinline__

DEVINL U16 f2bf(float f) {
    unsigned u = __float_as_uint(f);
    return (U16)((u + 0x7FFFu + ((u >> 16) & 1u)) >> 16);  // RN-even
}
DEVINL float bf2f(U16 s) { return __uint_as_float(((unsigned)s) << 16); }

DEVINL void gld16(const void* g, void* l) {
    __builtin_amdgcn_global_load_lds(
        (const __attribute__((address_space(1))) void*)g,
        (__attribute__((address_space(3))) void*)l, 16, 0, 0);
}

#define MFMA_BF16 __builtin_amdgcn_mfma_f32_16x16x32_bf16

// ---------------- weight transpose + cast: wt[n][k] = (bf16) w[k][n] ----------------
__global__ __launch_bounds__(256) void tcast_kernel(const float* __restrict__ w,
                                                    U16* __restrict__ wt, int K, int N) {
    __shared__ float tile[32][33];
    int n0 = blockIdx.x * 32, k0 = blockIdx.y * 32;
    int tx = threadIdx.x, ty = threadIdx.y;  // 32 x 8
#pragma unroll
    for (int i = 0; i < 32; i += 8) tile[ty + i][tx] = w[(size_t)(k0 + ty + i) * N + (n0 + tx)];
    __syncthreads();
#pragma unroll
    for (int i = 0; i < 32; i += 8) wt[(size_t)(n0 + ty + i) * K + (k0 + tx)] = f2bf(tile[tx][ty + i]);
}

// ---------------- LayerNorm over 512, one wave per row, bf16 out ----------------
__global__ __launch_bounds__(256) void ln_kernel(const float* __restrict__ x,
                                                 const float* __restrict__ g,
                                                 const float* __restrict__ b,
                                                 U16* __restrict__ out) {
    int lane = threadIdx.x & 63;
    size_t row = (size_t)blockIdx.x * 4 + (threadIdx.x >> 6);
    const float4* xr = (const float4*)(x + row * 512);
    float4 v0 = xr[lane], v1 = xr[lane + 64];
    float s = (v0.x + v0.y) + (v0.z + v0.w) + (v1.x + v1.y) + (v1.z + v1.w);
    float sq = (v0.x * v0.x + v0.y * v0.y + v0.z * v0.z + v0.w * v0.w) +
               (v1.x * v1.x + v1.y * v1.y + v1.z * v1.z + v1.w * v1.w);
#pragma unroll
    for (int m = 1; m < 64; m <<= 1) { s += __shfl_xor(s, m); sq += __shfl_xor(sq, m); }
    float mu = s * (1.f / 512.f);
    float var = sq * (1.f / 512.f) - mu * mu;
    float rs = rsqrtf(var + 1e-5f);
    const float4* g4 = (const float4*)g;
    const float4* b4 = (const float4*)b;
    float4 gv = g4[lane], bv = b4[lane];
    ushort4 o;
    o.x = f2bf((v0.x - mu) * rs * gv.x + bv.x);
    o.y = f2bf((v0.y - mu) * rs * gv.y + bv.y);
    o.z = f2bf((v0.z - mu) * rs * gv.z + bv.z);
    o.w = f2bf((v0.w - mu) * rs * gv.w + bv.w);
    ((ushort4*)(out + row * 512))[lane] = o;
    gv = g4[lane + 64]; bv = b4[lane + 64];
    o.x = f2bf((v1.x - mu) * rs * gv.x + bv.x);
    o.y = f2bf((v1.y - mu) * rs * gv.y + bv.y);
    o.z = f2bf((v1.z - mu) * rs * gv.z + bv.z);
    o.w = f2bf((v1.w - mu) * rs * gv.w + bv.w);
    ((ushort4*)(out + row * 512))[lane + 64] = o;
}

// ---------------- 128x256 ring-3 GEMM, 2 blocks/CU ----------------
// C[M,N] = A[M,K](bf16) * Bt[N,K](bf16)^T + bias (+gelu / +resid)
// 512 threads = 8 waves (2M x 4N), wave tile 64x64 (acc[4][4]=64 regs -> 4 waves/SIMD),
// BK=32, ring-3 LDS (3 x 24KB = 72KB; 2 blocks/CU = 144KB <= 160KB).
// Tile t: s_waitcnt vmcnt(3)  [counted: tile t's 3 loads land, t+1's 3 STAY in flight],
// one s_barrier, stage tile t+2 (3 gld16/thread), 8 ds_read_b128, 16 MFMA (all-distinct acc).
// Swizzle for 64B rows: phys 16B chunk = logical ^ ((row>>2)&3)  [8 lanes/bank-quad uniform]
// via pre-swizzled global source + XOR'd ds_read chunk offset.
// EPI 0: bf16 out (bias); EPI 1: fp32 out (bias+resid); EPI 2: bf16 out (bias+gelu)
template <int EPI>
__global__ __launch_bounds__(512, 4) void gemm_rt(const U16* __restrict__ A,
                                                  const U16* __restrict__ Bt,
                                                  const float* __restrict__ bias,
                                                  const float* __restrict__ resid,
                                                  U16* __restrict__ outb,
                                                  float* __restrict__ outf,
                                                  int M, int N, int K, int gridN) {
    // ring buffer b at b*12288 U16: A[128][32] at +0, B half0 at +4096, B half1 at +8192
    __shared__ __align__(16) U16 smem[36864];

    const int tid = threadIdx.x;
    const int lane = tid & 63, wv = tid >> 6;
    const int lo = lane & 15, hi = lane >> 4;
    const int wm = wv >> 2, wn = wv & 3;  // 2 x 4 wave grid, wave tile 64x64

    const int nwg = gridDim.x, bid = blockIdx.x;
    const int swzb = (bid & 7) * (nwg >> 3) + (bid >> 3);
    const int bn = swzb % gridN, bm = swzb / gridN;

    // staging: row sr = tid>>2 (0..127), phys chunk tid&3; logical = phys ^ ((sr>>2)&3)
    const int sr = tid >> 2;
    const int lc = (tid & 3) ^ ((sr >> 2) & 3);
    const U16* gA0 = A + (size_t)(bm * 128 + sr) * K + lc * 8;
    const U16* gB0 = Bt + (size_t)(bn * 256 + sr) * K + lc * 8;

// stage K-tile t2 into ring buffer t2%3 (3 gld16/thread: A rows 0-127, B rows 0-127, 128-255)
#define STAGE(t2)                                                     \
    do {                                                              \
        U16* _l = smem + ((t2) % 3) * 12288 + tid * 8;                \
        const U16* _ga = gA0 + (size_t)(t2) * 32;                     \
        const U16* _gb = gB0 + (size_t)(t2) * 32;                     \
        gld16(_ga, _l);                                               \
        gld16(_gb, _l + 4096);                                        \
        gld16(_gb + (size_t)128 * K, _l + 8192);                      \
    } while (0)

    // swizzled 16B-chunk offset for ds_read (U16 units)
    const int ck = (hi ^ ((lo >> 2) & 3)) << 3;

    f32x4 acc[4][4] = {};

    const int nt = K >> 5;
    STAGE(0);
    STAGE(1);

    for (int t = 0; t < nt; ++t) {
        if (t + 1 < nt) {
            asm volatile("s_waitcnt vmcnt(3)" ::: "memory");  // t's 3 landed; t+1's stay in flight
        } else {
            asm volatile("s_waitcnt vmcnt(0)" ::: "memory");  // last tile: only its own 3 outstanding
        }
        __builtin_amdgcn_s_barrier();
        if (t + 2 < nt) STAGE(t + 2);

        const int cb = (t % 3) * 12288;
        const U16* Ab = smem + cb + (wm * 64 + lo) * 32 + ck;
        const U16* Bb = smem + cb + 4096 + (wn >> 1) * 4096 + ((wn & 1) * 64 + lo) * 32 + ck;

        bf16x8 af[4], bg[4];
#pragma unroll
        for (int i = 0; i < 4; ++i) af[i] = *(const bf16x8*)(Ab + i * 512);
#pragma unroll
        for (int j = 0; j < 4; ++j) bg[j] = *(const bf16x8*)(Bb + j * 512);

        __builtin_amdgcn_s_setprio(1);
#pragma unroll
        for (int i = 0; i < 4; ++i)
#pragma unroll
            for (int j = 0; j < 4; ++j)
                acc[i][j] = MFMA_BF16(af[i], bg[j], acc[i][j], 0, 0, 0);
        __builtin_amdgcn_s_setprio(0);
        // next tile's top barrier fences buffer reuse (ring-3: overwrite target was
        // last read at tile t-1, finished before this tile's barrier)
    }

    // ---- epilogue: direct stores ----
    const int row0 = bm * 128 + wm * 64 + hi * 4;
    const int col0 = bn * 256 + wn * 64 + lo;
    float bc[4];
#pragma unroll
    for (int j = 0; j < 4; ++j) bc[j] = bias[col0 + j * 16];

    if (EPI == 1) {
#pragma unroll
        for (int i = 0; i < 4; ++i)
#pragma unroll
            for (int r = 0; r < 4; ++r) {
                const size_t rowb = (size_t)(row0 + i * 16 + r) * N;
#pragma unroll
                for (int j = 0; j < 4; ++j) {
                    const size_t idx = rowb + col0 + j * 16;
                    outf[idx] = acc[i][j][r] + bc[j] + resid[idx];
                }
            }
    } else {
#pragma unroll
        for (int i = 0; i < 4; ++i)
#pragma unroll
            for (int j = 0; j < 4; ++j)
#pragma unroll
                for (int r = 0; r < 4; ++r) {
                    float v = acc[i][j][r] + bc[j];
                    if (EPI == 2) v = 0.5f * v * (1.f + erff(v * 0.70710678118654752f));
                    outb[(size_t)(row0 + i * 16 + r) * N + col0 + j * 16] = f2bf(v);
                }
    }
#undef STAGE
}

// ---------------- windowed attention: one block per (window, head) ----------------
// qkv: [32768][1536] bf16, layout [3][8][64] in last dim. o: [32768][512] bf16.
__global__ __launch_bounds__(256) void attn_kernel(const U16* __restrict__ qkv,
                                                   U16* __restrict__ o) {
    const int blk = blockIdx.x;
    const int w = blk >> 3, h = blk & 7;
    const int tid = threadIdx.x;
    const int lane = tid & 63, wv = tid >> 6;
    const int lo = lane & 15, hi = lane >> 4;

    __shared__ __align__(16) U16 Qs[64][72];
    __shared__ __align__(16) U16 Ks[64][72];
    __shared__ __align__(16) U16 Vt[64][72];  // V transposed: Vt[d][j]
    __shared__ __align__(16) U16 Ps[4][16][72];

    {
        const int r = tid >> 2;
        const int c0 = (tid & 3) << 4;
        const U16* p = qkv + (size_t)(w * 64 + r) * 1536 + h * 64 + c0;
        *(bf16x8*)&Ks[r][c0] = *(const bf16x8*)(p + 512);
        *(bf16x8*)&Ks[r][c0 + 8] = *(const bf16x8*)(p + 520);
        const U16* pv = p + 1024;
#pragma unroll
        for (int i = 0; i < 16; i++) Vt[c0 + i][r] = pv[i];
#pragma unroll
        for (int i = 0; i < 16; i++) Qs[r][c0 + i] = f2bf(bf2f(p[i]) * 0.125f);
    }
    __syncthreads();

    const int rb = wv * 16;  // this wave's 16 score rows
    f32x4 s[4] = {};
#pragma unroll
    for (int dc = 0; dc < 64; dc += 32) {
        bf16x8 a = *(const bf16x8*)&Qs[rb + lo][dc + hi * 8];
#pragma unroll
        for (int jb = 0; jb < 4; jb++) {
            bf16x8 bfr = *(const bf16x8*)&Ks[jb * 16 + lo][dc + hi * 8];
            s[jb] = MFMA_BF16(a, bfr, s[jb], 0, 0, 0);
        }
    }
#pragma unroll
    for (int r = 0; r < 4; r++) {
        float m = fmaxf(fmaxf(s[0][r], s[1][r]), fmaxf(s[2][r], s[3][r]));
#pragma unroll
        for (int msk = 1; msk < 16; msk <<= 1) m = fmaxf(m, __shfl_xor(m, msk));
        float e[4], sum = 0.f;
#pragma unroll
        for (int jb = 0; jb < 4; jb++) { e[jb] = expf(s[jb][r] - m); sum += e[jb]; }
#pragma unroll
        for (int msk = 1; msk < 16; msk <<= 1) sum += __shfl_xor(sum, msk);
        float inv = 1.f / sum;
#pragma unroll
        for (int jb = 0; jb < 4; jb++) Ps[wv][hi * 4 + r][jb * 16 + lo] = f2bf(e[jb] * inv);
    }
    __syncthreads();

    f32x4 oa[4] = {};
#pragma unroll
    for (int jc = 0; jc < 64; jc += 32) {
        bf16x8 a = *(const bf16x8*)&Ps[wv][lo][jc + hi * 8];
#pragma unroll
        for (int db = 0; db < 4; db++) {
            bf16x8 bfr = *(const bf16x8*)&Vt[db * 16 + lo][jc + hi * 8];
            oa[db] = MFMA_BF16(a, bfr, oa[db], 0, 0, 0);
        }
    }
#pragma unroll
    for (int db = 0; db < 4; db++)
#pragma unroll
        for (int r = 0; r < 4; r++)
            o[(size_t)(w * 64 + rb + hi * 4 + r) * 512 + h * 64 + db * 16 + lo] = f2bf(oa[db][r]);
}

// ---------------- launch ----------------
extern "C" void kernel_launch(void* const* d_in, const int* in_sizes, int n_in,
                              void* d_out, int out_size, void* d_ws, size_t ws_size,
                              hipStream_t stream) {
    const float* x = (const float*)d_in[0];
    const float* ln1_g = (const float*)d_in[1];
    const float* ln1_b = (const float*)d_in[2];
    const float* qkv_w = (const float*)d_in[3];
    const float* qkv_b = (const float*)d_in[4];
    const float* proj_w = (const float*)d_in[5];
    const float* proj_b = (const float*)d_in[6];
    const float* ln2_g = (const float*)d_in[7];
    const float* ln2_b = (const float*)d_in[8];
    const float* fc1_w = (const float*)d_in[9];
    const float* fc1_b = (const float*)d_in[10];
    const float* fc2_w = (const float*)d_in[11];
    const float* fc2_b = (const float*)d_in[12];
    float* out = (float*)d_out;

    char* ws = (char*)d_ws;
    U16* hbuf = (U16*)ws;                               // 32768*512 bf16
    U16* big = (U16*)(ws + 33554432);                   // 32768*2048 bf16 max
    U16* wt_qkv = (U16*)(ws + 33554432 + 134217728);    // 1536*512
    U16* wt_proj = wt_qkv + 1536 * 512;                 // 512*512
    U16* wt_fc1 = wt_proj + 512 * 512;                  // 2048*512
    U16* wt_fc2 = wt_fc1 + 2048 * 512;                  // 512*2048

    dim3 tb(32, 8);
    tcast_kernel<<<dim3(1536 / 32, 512 / 32), tb, 0, stream>>>(qkv_w, wt_qkv, 512, 1536);
    tcast_kernel<<<dim3(512 / 32, 512 / 32), tb, 0, stream>>>(proj_w, wt_proj, 512, 512);
    tcast_kernel<<<dim3(2048 / 32, 512 / 32), tb, 0, stream>>>(fc1_w, wt_fc1, 512, 2048);
    tcast_kernel<<<dim3(512 / 32, 2048 / 32), tb, 0, stream>>>(fc2_w, wt_fc2, 2048, 512);

    ln_kernel<<<8192, 256, 0, stream>>>(x, ln1_g, ln1_b, hbuf);
    gemm_rt<0><<<1536, 512, 0, stream>>>(hbuf, wt_qkv, qkv_b, nullptr, big, nullptr, 32768, 1536, 512, 6);
    attn_kernel<<<4096, 256, 0, stream>>>(big, hbuf);
    gemm_rt<1><<<512, 512, 0, stream>>>(hbuf, wt_proj, proj_b, x, nullptr, out, 32768, 512, 512, 2);
    ln_kernel<<<8192, 256, 0, stream>>>(out, ln2_g, ln2_b, hbuf);
    gemm_rt<2><<<2048, 512, 0, stream>>>(hbuf, wt_fc1, fc1_b, nullptr, big, nullptr, 32768, 2048, 512, 8);
    gemm_rt<1><<<512, 512, 0, stream>>>(big, wt_fc2, fc2_b, out, nullptr, out, 32768, 512, 2048, 2);
}

// Round 8
// 380.959 us; speedup vs baseline: 1.0854x; 1.0211x over previous
//
#include <hip/hip_runtime.h>
#include <hip/hip_bf16.h>
#include <cstdint>

typedef unsigned short U16;
typedef float f32x4 __attribute__((ext_vector_type(4)));
typedef __bf16 bf16x8 __attribute__((ext_vector_type(8)));

#define DEVINL __device__ __forceinline__

DEVINL U16 f2bf(float f) {
    unsigned u = __float_as_uint(f);
    return (U16)((u + 0x7FFFu + ((u >> 16) & 1u)) >> 16);  // RN-even
}
DEVINL float bf2f(U16 s) { return __uint_as_float(((unsigned)s) << 16); }

DEVINL void gld16(const void* g, void* l) {
    __builtin_amdgcn_global_load_lds(
        (const __attribute__((address_space(1))) void*)g,
        (__attribute__((address_space(3))) void*)l, 16, 0, 0);
}

#define MFMA_BF16 __builtin_amdgcn_mfma_f32_16x16x32_bf16

// ---------------- weight transpose + cast: wt[n][k] = (bf16) w[k][n] ----------------
__global__ __launch_bounds__(256) void tcast_kernel(const float* __restrict__ w,
                                                    U16* __restrict__ wt, int K, int N) {
    __shared__ float tile[32][33];
    int n0 = blockIdx.x * 32, k0 = blockIdx.y * 32;
    int tx = threadIdx.x, ty = threadIdx.y;  // 32 x 8
#pragma unroll
    for (int i = 0; i < 32; i += 8) tile[ty + i][tx] = w[(size_t)(k0 + ty + i) * N + (n0 + tx)];
    __syncthreads();
#pragma unroll
    for (int i = 0; i < 32; i += 8) wt[(size_t)(n0 + ty + i) * K + (k0 + tx)] = f2bf(tile[tx][ty + i]);
}

// ---------------- LayerNorm over 512, one wave per row, bf16 out ----------------
__global__ __launch_bounds__(256) void ln_kernel(const float* __restrict__ x,
                                                 const float* __restrict__ g,
                                                 const float* __restrict__ b,
                                                 U16* __restrict__ out) {
    int lane = threadIdx.x & 63;
    size_t row = (size_t)blockIdx.x * 4 + (threadIdx.x >> 6);
    const float4* xr = (const float4*)(x + row * 512);
    float4 v0 = xr[lane], v1 = xr[lane + 64];
    float s = (v0.x + v0.y) + (v0.z + v0.w) + (v1.x + v1.y) + (v1.z + v1.w);
    float sq = (v0.x * v0.x + v0.y * v0.y + v0.z * v0.z + v0.w * v0.w) +
               (v1.x * v1.x + v1.y * v1.y + v1.z * v1.z + v1.w * v1.w);
#pragma unroll
    for (int m = 1; m < 64; m <<= 1) { s += __shfl_xor(s, m); sq += __shfl_xor(sq, m); }
    float mu = s * (1.f / 512.f);
    float var = sq * (1.f / 512.f) - mu * mu;
    float rs = rsqrtf(var + 1e-5f);
    const float4* g4 = (const float4*)g;
    const float4* b4 = (const float4*)b;
    float4 gv = g4[lane], bv = b4[lane];
    ushort4 o;
    o.x = f2bf((v0.x - mu) * rs * gv.x + bv.x);
    o.y = f2bf((v0.y - mu) * rs * gv.y + bv.y);
    o.z = f2bf((v0.z - mu) * rs * gv.z + bv.z);
    o.w = f2bf((v0.w - mu) * rs * gv.w + bv.w);
    ((ushort4*)(out + row * 512))[lane] = o;
    gv = g4[lane + 64]; bv = b4[lane + 64];
    o.x = f2bf((v1.x - mu) * rs * gv.x + bv.x);
    o.y = f2bf((v1.y - mu) * rs * gv.y + bv.y);
    o.z = f2bf((v1.z - mu) * rs * gv.z + bv.z);
    o.w = f2bf((v1.w - mu) * rs * gv.w + bv.w);
    ((ushort4*)(out + row * 512))[lane + 64] = o;
}

// ---------------- 128x256 ring-3 GEMM, 2 blocks/CU, K templated + fully unrolled ------
// C[M,N] = A[M,K](bf16) * Bt[N,K](bf16)^T + bias (+gelu / +resid)
// 512 threads = 8 waves (2M x 4N), wave tile 64x64 (acc[4][4]=64 regs -> 4 waves/SIMD),
// BK=32, ring-3 LDS (3 x 24KB = 72KB; 2 blocks/CU = 144KB <= 160KB).
// Tile t: s_waitcnt vmcnt(3) [counted: t's 3 loads land, t+1's 3 STAY in flight],
// one s_barrier, stage tile t+2, 8 ds_read_b128, 16 MFMA. Full unroll folds all
// ring %3 and address math into immediates (R7: VALUBusy 80% from runtime indexing).
// Swizzle (group-of-8-lanes rule): phys 16B chunk = logical ^ ((row>>1)&3); within any
// 8 consecutive lanes {lo&1, chunk} bijects onto the 8 16B-slots of a 128B line.
// EPI 0: bf16 out (bias); EPI 1: fp32 out (bias+resid); EPI 2: bf16 out (bias+gelu-tanh)
template <int EPI, int K>
__global__ __launch_bounds__(512, 4) void gemm_rt(const U16* __restrict__ A,
                                                  const U16* __restrict__ Bt,
                                                  const float* __restrict__ bias,
                                                  const float* __restrict__ resid,
                                                  U16* __restrict__ outb,
                                                  float* __restrict__ outf,
                                                  int M, int N, int gridN) {
    // ring buffer b at b*12288 U16: A[128][32] at +0, B half0 at +4096, B half1 at +8192
    __shared__ __align__(16) U16 smem[36864];

    const int tid = threadIdx.x;
    const int lane = tid & 63, wv = tid >> 6;
    const int lo = lane & 15, hi = lane >> 4;
    const int wm = wv >> 2, wn = wv & 3;  // 2 x 4 wave grid, wave tile 64x64

    const int nwg = gridDim.x, bid = blockIdx.x;
    const int swzb = (bid & 7) * (nwg >> 3) + (bid >> 3);
    const int bn = swzb % gridN, bm = swzb / gridN;

    // staging: row sr = tid>>2 (0..127), phys chunk tid&3; logical = phys ^ ((sr>>1)&3)
    const int sr = tid >> 2;
    const int lc = (tid & 3) ^ ((sr >> 1) & 3);
    const U16* gA0 = A + (size_t)(bm * 128 + sr) * K + lc * 8;
    const U16* gB0 = Bt + (size_t)(bn * 256 + sr) * K + lc * 8;
    const U16* gB1 = gB0 + (size_t)128 * K;

// stage K-tile t2 into ring buffer t2%3 (3 gld16/thread); t2 compile-time constant
#define STAGE(t2)                                                     \
    do {                                                              \
        U16* _l = smem + ((t2) % 3) * 12288 + tid * 8;                \
        gld16(gA0 + (t2) * 32, _l);                                   \
        gld16(gB0 + (t2) * 32, _l + 4096);                            \
        gld16(gB1 + (t2) * 32, _l + 8192);                            \
    } while (0)

    // swizzled 16B-chunk offset for ds_read (U16 units): chunk = hi ^ ((lo>>1)&3)
    const int ck = (hi ^ ((lo >> 1) & 3)) << 3;

    f32x4 acc[4][4] = {};

    constexpr int NT = K >> 5;
    STAGE(0);
    STAGE(1);

#pragma unroll
    for (int t = 0; t < NT; ++t) {
        if (t + 1 < NT) {
            asm volatile("s_waitcnt vmcnt(3)" ::: "memory");  // t's 3 landed; t+1's stay in flight
        } else {
            asm volatile("s_waitcnt vmcnt(0)" ::: "memory");  // last tile
        }
        __builtin_amdgcn_s_barrier();
        if (t + 2 < NT) STAGE(t + 2);

        const int cb = (t % 3) * 12288;
        const U16* Ab = smem + cb + (wm * 64 + lo) * 32 + ck;
        const U16* Bb = smem + cb + 4096 + (wn >> 1) * 4096 + ((wn & 1) * 64 + lo) * 32 + ck;

        bf16x8 af[4], bg[4];
#pragma unroll
        for (int i = 0; i < 4; ++i) af[i] = *(const bf16x8*)(Ab + i * 512);
#pragma unroll
        for (int j = 0; j < 4; ++j) bg[j] = *(const bf16x8*)(Bb + j * 512);

        __builtin_amdgcn_s_setprio(1);
#pragma unroll
        for (int i = 0; i < 4; ++i)
#pragma unroll
            for (int j = 0; j < 4; ++j)
                acc[i][j] = MFMA_BF16(af[i], bg[j], acc[i][j], 0, 0, 0);
        __builtin_amdgcn_s_setprio(0);
        // next tile's top barrier fences ring reuse (buffer (t+2)%3 was last read at t-1)
    }

    // ---- epilogue: direct stores ----
    const int row0 = bm * 128 + wm * 64 + hi * 4;
    const int col0 = bn * 256 + wn * 64 + lo;
    float bc[4];
#pragma unroll
    for (int j = 0; j < 4; ++j) bc[j] = bias[col0 + j * 16];

    if (EPI == 1) {
#pragma unroll
        for (int i = 0; i < 4; ++i)
#pragma unroll
            for (int r = 0; r < 4; ++r) {
                const size_t rowb = (size_t)(row0 + i * 16 + r) * N;
#pragma unroll
                for (int j = 0; j < 4; ++j) {
                    const size_t idx = rowb + col0 + j * 16;
                    outf[idx] = acc[i][j][r] + bc[j] + resid[idx];
                }
            }
    } else {
#pragma unroll
        for (int i = 0; i < 4; ++i)
#pragma unroll
            for (int j = 0; j < 4; ++j)
#pragma unroll
                for (int r = 0; r < 4; ++r) {
                    float v = acc[i][j][r] + bc[j];
                    if (EPI == 2) {
                        // tanh-form GELU: v*sigmoid(2u), u = 0.79788456(v + 0.044715 v^3)
                        float u = v * (0.7978845608028654f + 0.0356774081f * v * v);
                        v = v / (1.f + __expf(-2.f * u));
                    }
                    outb[(size_t)(row0 + i * 16 + r) * N + col0 + j * 16] = f2bf(v);
                }
    }
#undef STAGE
}

// ---------------- windowed attention: one block per (window, head) ----------------
// qkv: [32768][1536] bf16, layout [3][8][64] in last dim. o: [32768][512] bf16.
__global__ __launch_bounds__(256) void attn_kernel(const U16* __restrict__ qkv,
                                                   U16* __restrict__ o) {
    const int blk = blockIdx.x;
    const int w = blk >> 3, h = blk & 7;
    const int tid = threadIdx.x;
    const int lane = tid & 63, wv = tid >> 6;
    const int lo = lane & 15, hi = lane >> 4;

    __shared__ __align__(16) U16 Qs[64][72];
    __shared__ __align__(16) U16 Ks[64][72];
    __shared__ __align__(16) U16 Vt[64][72];  // V transposed: Vt[d][j]
    __shared__ __align__(16) U16 Ps[4][16][72];

    {
        const int r = tid >> 2;
        const int c0 = (tid & 3) << 4;
        const U16* p = qkv + (size_t)(w * 64 + r) * 1536 + h * 64 + c0;
        *(bf16x8*)&Ks[r][c0] = *(const bf16x8*)(p + 512);
        *(bf16x8*)&Ks[r][c0 + 8] = *(const bf16x8*)(p + 520);
        const U16* pv = p + 1024;
#pragma unroll
        for (int i = 0; i < 16; i++) Vt[c0 + i][r] = pv[i];
#pragma unroll
        for (int i = 0; i < 16; i++) Qs[r][c0 + i] = f2bf(bf2f(p[i]) * 0.125f);
    }
    __syncthreads();

    const int rb = wv * 16;  // this wave's 16 score rows
    f32x4 s[4] = {};
#pragma unroll
    for (int dc = 0; dc < 64; dc += 32) {
        bf16x8 a = *(const bf16x8*)&Qs[rb + lo][dc + hi * 8];
#pragma unroll
        for (int jb = 0; jb < 4; jb++) {
            bf16x8 bfr = *(const bf16x8*)&Ks[jb * 16 + lo][dc + hi * 8];
            s[jb] = MFMA_BF16(a, bfr, s[jb], 0, 0, 0);
        }
    }
#pragma unroll
    for (int r = 0; r < 4; r++) {
        float m = fmaxf(fmaxf(s[0][r], s[1][r]), fmaxf(s[2][r], s[3][r]));
#pragma unroll
        for (int msk = 1; msk < 16; msk <<= 1) m = fmaxf(m, __shfl_xor(m, msk));
        float e[4], sum = 0.f;
#pragma unroll
        for (int jb = 0; jb < 4; jb++) { e[jb] = expf(s[jb][r] - m); sum += e[jb]; }
#pragma unroll
        for (int msk = 1; msk < 16; msk <<= 1) sum += __shfl_xor(sum, msk);
        float inv = 1.f / sum;
#pragma unroll
        for (int jb = 0; jb < 4; jb++) Ps[wv][hi * 4 + r][jb * 16 + lo] = f2bf(e[jb] * inv);
    }
    __syncthreads();

    f32x4 oa[4] = {};
#pragma unroll
    for (int jc = 0; jc < 64; jc += 32) {
        bf16x8 a = *(const bf16x8*)&Ps[wv][lo][jc + hi * 8];
#pragma unroll
        for (int db = 0; db < 4; db++) {
            bf16x8 bfr = *(const bf16x8*)&Vt[db * 16 + lo][jc + hi * 8];
            oa[db] = MFMA_BF16(a, bfr, oa[db], 0, 0, 0);
        }
    }
#pragma unroll
    for (int db = 0; db < 4; db++)
#pragma unroll
        for (int r = 0; r < 4; r++)
            o[(size_t)(w * 64 + rb + hi * 4 + r) * 512 + h * 64 + db * 16 + lo] = f2bf(oa[db][r]);
}

// ---------------- launch ----------------
extern "C" void kernel_launch(void* const* d_in, const int* in_sizes, int n_in,
                              void* d_out, int out_size, void* d_ws, size_t ws_size,
                              hipStream_t stream) {
    const float* x = (const float*)d_in[0];
    const float* ln1_g = (const float*)d_in[1];
    const float* ln1_b = (const float*)d_in[2];
    const float* qkv_w = (const float*)d_in[3];
    const float* qkv_b = (const float*)d_in[4];
    const float* proj_w = (const float*)d_in[5];
    const float* proj_b = (const float*)d_in[6];
    const float* ln2_g = (const float*)d_in[7];
    const float* ln2_b = (const float*)d_in[8];
    const float* fc1_w = (const float*)d_in[9];
    const float* fc1_b = (const float*)d_in[10];
    const float* fc2_w = (const float*)d_in[11];
    const float* fc2_b = (const float*)d_in[12];
    float* out = (float*)d_out;

    char* ws = (char*)d_ws;
    U16* hbuf = (U16*)ws;                               // 32768*512 bf16
    U16* big = (U16*)(ws + 33554432);                   // 32768*2048 bf16 max
    U16* wt_qkv = (U16*)(ws + 33554432 + 134217728);    // 1536*512
    U16* wt_proj = wt_qkv + 1536 * 512;                 // 512*512
    U16* wt_fc1 = wt_proj + 512 * 512;                  // 2048*512
    U16* wt_fc2 = wt_fc1 + 2048 * 512;                  // 512*2048

    dim3 tb(32, 8);
    tcast_kernel<<<dim3(1536 / 32, 512 / 32), tb, 0, stream>>>(qkv_w, wt_qkv, 512, 1536);
    tcast_kernel<<<dim3(512 / 32, 512 / 32), tb, 0, stream>>>(proj_w, wt_proj, 512, 512);
    tcast_kernel<<<dim3(2048 / 32, 512 / 32), tb, 0, stream>>>(fc1_w, wt_fc1, 512, 2048);
    tcast_kernel<<<dim3(512 / 32, 2048 / 32), tb, 0, stream>>>(fc2_w, wt_fc2, 2048, 512);

    ln_kernel<<<8192, 256, 0, stream>>>(x, ln1_g, ln1_b, hbuf);
    gemm_rt<0, 512><<<1536, 512, 0, stream>>>(hbuf, wt_qkv, qkv_b, nullptr, big, nullptr, 32768, 1536, 6);
    attn_kernel<<<4096, 256, 0, stream>>>(big, hbuf);
    gemm_rt<1, 512><<<512, 512, 0, stream>>>(hbuf, wt_proj, proj_b, x, nullptr, out, 32768, 512, 2);
    ln_kernel<<<8192, 256, 0, stream>>>(out, ln2_g, ln2_b, hbuf);
    gemm_rt<2, 512><<<2048, 512, 0, stream>>>(hbuf, wt_fc1, fc1_b, nullptr, big, nullptr, 32768, 2048, 8);
    gemm_rt<1, 2048><<<512, 512, 0, stream>>>(big, wt_fc2, fc2_b, out, nullptr, out, 32768, 512, 2);
}

// Round 9
// 375.290 us; speedup vs baseline: 1.1018x; 1.0151x over previous
//
#include <hip/hip_runtime.h>
#include <hip/hip_bf16.h>
#include <cstdint>

typedef unsigned short U16;
typedef float f32x4 __attribute__((ext_vector_type(4)));
typedef __bf16 bf16x8 __attribute__((ext_vector_type(8)));

#define DEVINL __device__ __forceinline__

DEVINL U16 f2bf(float f) {
    unsigned u = __float_as_uint(f);
    return (U16)((u + 0x7FFFu + ((u >> 16) & 1u)) >> 16);  // RN-even
}
DEVINL float bf2f(U16 s) { return __uint_as_float(((unsigned)s) << 16); }

DEVINL void gld16(const void* g, void* l) {
    __builtin_amdgcn_global_load_lds(
        (const __attribute__((address_space(1))) void*)g,
        (__attribute__((address_space(3))) void*)l, 16, 0, 0);
}

#define MFMA_BF16 __builtin_amdgcn_mfma_f32_16x16x32_bf16

// ---------------- weight transpose + cast: wt[n][k] = (bf16) w[k][n] ----------------
__global__ __launch_bounds__(256) void tcast_kernel(const float* __restrict__ w,
                                                    U16* __restrict__ wt, int K, int N) {
    __shared__ float tile[32][33];
    int n0 = blockIdx.x * 32, k0 = blockIdx.y * 32;
    int tx = threadIdx.x, ty = threadIdx.y;  // 32 x 8
#pragma unroll
    for (int i = 0; i < 32; i += 8) tile[ty + i][tx] = w[(size_t)(k0 + ty + i) * N + (n0 + tx)];
    __syncthreads();
#pragma unroll
    for (int i = 0; i < 32; i += 8) wt[(size_t)(n0 + ty + i) * K + (k0 + tx)] = f2bf(tile[tx][ty + i]);
}

// ---------------- LayerNorm over 512, one wave per row, bf16 out ----------------
__global__ __launch_bounds__(256) void ln_kernel(const float* __restrict__ x,
                                                 const float* __restrict__ g,
                                                 const float* __restrict__ b,
                                                 U16* __restrict__ out) {
    int lane = threadIdx.x & 63;
    size_t row = (size_t)blockIdx.x * 4 + (threadIdx.x >> 6);
    const float4* xr = (const float4*)(x + row * 512);
    float4 v0 = xr[lane], v1 = xr[lane + 64];
    float s = (v0.x + v0.y) + (v0.z + v0.w) + (v1.x + v1.y) + (v1.z + v1.w);
    float sq = (v0.x * v0.x + v0.y * v0.y + v0.z * v0.z + v0.w * v0.w) +
               (v1.x * v1.x + v1.y * v1.y + v1.z * v1.z + v1.w * v1.w);
#pragma unroll
    for (int m = 1; m < 64; m <<= 1) { s += __shfl_xor(s, m); sq += __shfl_xor(sq, m); }
    float mu = s * (1.f / 512.f);
    float var = sq * (1.f / 512.f) - mu * mu;
    float rs = rsqrtf(var + 1e-5f);
    const float4* g4 = (const float4*)g;
    const float4* b4 = (const float4*)b;
    float4 gv = g4[lane], bv = b4[lane];
    ushort4 o;
    o.x = f2bf((v0.x - mu) * rs * gv.x + bv.x);
    o.y = f2bf((v0.y - mu) * rs * gv.y + bv.y);
    o.z = f2bf((v0.z - mu) * rs * gv.z + bv.z);
    o.w = f2bf((v0.w - mu) * rs * gv.w + bv.w);
    ((ushort4*)(out + row * 512))[lane] = o;
    gv = g4[lane + 64]; bv = b4[lane + 64];
    o.x = f2bf((v1.x - mu) * rs * gv.x + bv.x);
    o.y = f2bf((v1.y - mu) * rs * gv.y + bv.y);
    o.z = f2bf((v1.z - mu) * rs * gv.z + bv.z);
    o.w = f2bf((v1.w - mu) * rs * gv.w + bv.w);
    ((ushort4*)(out + row * 512))[lane + 64] = o;
}

// ---------------- 128x128 ring-2 GEMM, 4 blocks/CU (independence re-tile) ----------------
// C[M,N] = A[M,K](bf16) * Bt[N,K](bf16)^T + bias (+gelu / +resid)
// 256 threads = 4 waves (2M x 2N), wave tile 64x64 (acc[4][4] = 64 regs), BK=32.
// LDS: ring-2 x 16KB = 32KB/block -> 4 blocks/CU = 16 waves/CU, each SIMD hosting 4 waves
// from 4 INDEPENDENT blocks (separate barrier groups -> m114-style overlap).
// Tile t: STAGE(t+1) [4 gld16]; s_waitcnt vmcnt(4) [counted: tile t landed, t+1's 4 stay
// in flight -- never drains to 0 until the true last tile]; barrier; 8 ds_read_b128 +
// 16 MFMA; barrier (read-complete fence: ring-2 overwrite of buf t&1 happens at iter t+1's
// STAGE(t+2), which is after this barrier on every wave).
// Swizzle (group-of-8-lanes rule, measured 0 conflicts in R8): phys 16B chunk =
// logical ^ ((row>>1)&3), pre-swizzled global source + XOR'd ds_read offset.
// K templated: unrolled in static 16-tile chunks + static tail (folds ring parity + addrs).
// EPI 0: bf16 out (bias); EPI 1: fp32 out (bias+resid); EPI 2: bf16 out (bias+gelu-tanh)
template <int EPI, int K>
__global__ __launch_bounds__(256, 4) void gemm_rt(const U16* __restrict__ A,
                                                  const U16* __restrict__ Bt,
                                                  const float* __restrict__ bias,
                                                  const float* __restrict__ resid,
                                                  U16* __restrict__ outb,
                                                  float* __restrict__ outf,
                                                  int M, int N, int gridN) {
    // ring buffer b at b*8192 U16: A[128][32] at +0, B[128][32] at +4096
    __shared__ __align__(16) U16 smem[16384];

    const int tid = threadIdx.x;
    const int lane = tid & 63, wv = tid >> 6;
    const int lo = lane & 15, hi = lane >> 4;
    const int wm = wv >> 1, wn = wv & 1;  // 2 x 2 wave grid, wave tile 64x64

    const int nwg = gridDim.x, bid = blockIdx.x;
    const int swzb = (bid & 7) * (nwg >> 3) + (bid >> 3);
    const int bn = swzb % gridN, bm = swzb / gridN;

    // staging: row sr = tid>>2 (0..63; +64 for second line), phys chunk tid&3;
    // logical chunk = phys ^ ((row>>1)&3); (row+64)>>1 has same &3 -> one source col
    const int sr = tid >> 2;
    const int lc = (tid & 3) ^ ((sr >> 1) & 3);
    const U16* gA0 = A + (size_t)(bm * 128 + sr) * K + lc * 8;
    const U16* gA1 = gA0 + (size_t)64 * K;
    const U16* gB0 = Bt + (size_t)(bn * 128 + sr) * K + lc * 8;
    const U16* gB1 = gB0 + (size_t)64 * K;

// stage K-tile t2 into ring buffer t2&1 (4 gld16/thread)
#define STAGE(t2)                                                     \
    do {                                                              \
        U16* _l = smem + ((t2) & 1) * 8192 + tid * 8;                 \
        gld16(gA0 + (t2) * 32, _l);                                   \
        gld16(gA1 + (t2) * 32, _l + 2048);                            \
        gld16(gB0 + (t2) * 32, _l + 4096);                            \
        gld16(gB1 + (t2) * 32, _l + 6144);                            \
    } while (0)

    // swizzled 16B-chunk offset for ds_read (U16 units): chunk = hi ^ ((lo>>1)&3)
    const int ck = (hi ^ ((lo >> 1) & 3)) << 3;

    f32x4 acc[4][4] = {};

    constexpr int NT = K >> 5;
    static_assert(NT >= 16 && (NT % 16) == 0, "K must be a multiple of 512");

    STAGE(0);

    auto tile = [&](int t, bool pf) __attribute__((always_inline)) {
        if (pf) {
            STAGE(t + 1);
            asm volatile("s_waitcnt vmcnt(4)" ::: "memory");  // tile t landed; t+1 in flight
        } else {
            asm volatile("s_waitcnt vmcnt(0)" ::: "memory");  // true last tile only
        }
        __builtin_amdgcn_s_barrier();

        const int cb = (t & 1) * 8192;
        const U16* Ab = smem + cb + (wm * 64 + lo) * 32 + ck;
        const U16* Bb = smem + cb + 4096 + (wn * 64 + lo) * 32 + ck;

        bf16x8 af[4], bg[4];
#pragma unroll
        for (int i = 0; i < 4; ++i) af[i] = *(const bf16x8*)(Ab + i * 512);
#pragma unroll
        for (int j = 0; j < 4; ++j) bg[j] = *(const bf16x8*)(Bb + j * 512);

        __builtin_amdgcn_s_setprio(1);
#pragma unroll
        for (int i = 0; i < 4; ++i)
#pragma unroll
            for (int j = 0; j < 4; ++j)
                acc[i][j] = MFMA_BF16(af[i], bg[j], acc[i][j], 0, 0, 0);
        __builtin_amdgcn_s_setprio(0);
        __builtin_amdgcn_s_barrier();  // all waves done reading buf (t&1) before it's restaged
    };

    // main: all 16-tile chunks except the last
    for (int t0 = 0; t0 + 16 < NT; t0 += 16) {
#pragma unroll
        for (int tt = 0; tt < 16; ++tt) tile(t0 + tt, true);
    }
    // tail: last 16 tiles, fully static
#pragma unroll
    for (int tt = 0; tt < 16; ++tt) {
        const int t = NT - 16 + tt;
        tile(t, t + 1 < NT);
    }

    // ---- epilogue: direct stores ----
    const int row0 = bm * 128 + wm * 64 + hi * 4;
    const int col0 = bn * 128 + wn * 64 + lo;
    float bc[4];
#pragma unroll
    for (int j = 0; j < 4; ++j) bc[j] = bias[col0 + j * 16];

    if (EPI == 1) {
#pragma unroll
        for (int i = 0; i < 4; ++i)
#pragma unroll
            for (int r = 0; r < 4; ++r) {
                const size_t rowb = (size_t)(row0 + i * 16 + r) * N;
#pragma unroll
                for (int j = 0; j < 4; ++j) {
                    const size_t idx = rowb + col0 + j * 16;
                    outf[idx] = acc[i][j][r] + bc[j] + resid[idx];
                }
            }
    } else {
#pragma unroll
        for (int i = 0; i < 4; ++i)
#pragma unroll
            for (int j = 0; j < 4; ++j)
#pragma unroll
                for (int r = 0; r < 4; ++r) {
                    float v = acc[i][j][r] + bc[j];
                    if (EPI == 2) {
                        // tanh-form GELU: v*sigmoid(2u), u = 0.79788456(v + 0.044715 v^3)
                        float u = v * (0.7978845608028654f + 0.0356774081f * v * v);
                        v = v / (1.f + __expf(-2.f * u));
                    }
                    outb[(size_t)(row0 + i * 16 + r) * N + col0 + j * 16] = f2bf(v);
                }
    }
#undef STAGE
}

// ---------------- windowed attention: one block per (window, head) ----------------
// qkv: [32768][1536] bf16, layout [3][8][64] in last dim. o: [32768][512] bf16.
__global__ __launch_bounds__(256) void attn_kernel(const U16* __restrict__ qkv,
                                                   U16* __restrict__ o) {
    const int blk = blockIdx.x;
    const int w = blk >> 3, h = blk & 7;
    const int tid = threadIdx.x;
    const int lane = tid & 63, wv = tid >> 6;
    const int lo = lane & 15, hi = lane >> 4;

    __shared__ __align__(16) U16 Qs[64][72];
    __shared__ __align__(16) U16 Ks[64][72];
    __shared__ __align__(16) U16 Vt[64][72];  // V transposed: Vt[d][j]
    __shared__ __align__(16) U16 Ps[4][16][72];

    {
        const int r = tid >> 2;
        const int c0 = (tid & 3) << 4;
        const U16* p = qkv + (size_t)(w * 64 + r) * 1536 + h * 64 + c0;
        *(bf16x8*)&Ks[r][c0] = *(const bf16x8*)(p + 512);
        *(bf16x8*)&Ks[r][c0 + 8] = *(const bf16x8*)(p + 520);
        const U16* pv = p + 1024;
#pragma unroll
        for (int i = 0; i < 16; i++) Vt[c0 + i][r] = pv[i];
#pragma unroll
        for (int i = 0; i < 16; i++) Qs[r][c0 + i] = f2bf(bf2f(p[i]) * 0.125f);
    }
    __syncthreads();

    const int rb = wv * 16;  // this wave's 16 score rows
    f32x4 s[4] = {};
#pragma unroll
    for (int dc = 0; dc < 64; dc += 32) {
        bf16x8 a = *(const bf16x8*)&Qs[rb + lo][dc + hi * 8];
#pragma unroll
        for (int jb = 0; jb < 4; jb++) {
            bf16x8 bfr = *(const bf16x8*)&Ks[jb * 16 + lo][dc + hi * 8];
            s[jb] = MFMA_BF16(a, bfr, s[jb], 0, 0, 0);
        }
    }
#pragma unroll
    for (int r = 0; r < 4; r++) {
        float m = fmaxf(fmaxf(s[0][r], s[1][r]), fmaxf(s[2][r], s[3][r]));
#pragma unroll
        for (int msk = 1; msk < 16; msk <<= 1) m = fmaxf(m, __shfl_xor(m, msk));
        float e[4], sum = 0.f;
#pragma unroll
        for (int jb = 0; jb < 4; jb++) { e[jb] = expf(s[jb][r] - m); sum += e[jb]; }
#pragma unroll
        for (int msk = 1; msk < 16; msk <<= 1) sum += __shfl_xor(sum, msk);
        float inv = 1.f / sum;
#pragma unroll
        for (int jb = 0; jb < 4; jb++) Ps[wv][hi * 4 + r][jb * 16 + lo] = f2bf(e[jb] * inv);
    }
    __syncthreads();

    f32x4 oa[4] = {};
#pragma unroll
    for (int jc = 0; jc < 64; jc += 32) {
        bf16x8 a = *(const bf16x8*)&Ps[wv][lo][jc + hi * 8];
#pragma unroll
        for (int db = 0; db < 4; db++) {
            bf16x8 bfr = *(const bf16x8*)&Vt[db * 16 + lo][jc + hi * 8];
            oa[db] = MFMA_BF16(a, bfr, oa[db], 0, 0, 0);
        }
    }
#pragma unroll
    for (int db = 0; db < 4; db++)
#pragma unroll
        for (int r = 0; r < 4; r++)
            o[(size_t)(w * 64 + rb + hi * 4 + r) * 512 + h * 64 + db * 16 + lo] = f2bf(oa[db][r]);
}

// ---------------- launch ----------------
extern "C" void kernel_launch(void* const* d_in, const int* in_sizes, int n_in,
                              void* d_out, int out_size, void* d_ws, size_t ws_size,
                              hipStream_t stream) {
    const float* x = (const float*)d_in[0];
    const float* ln1_g = (const float*)d_in[1];
    const float* ln1_b = (const float*)d_in[2];
    const float* qkv_w = (const float*)d_in[3];
    const float* qkv_b = (const float*)d_in[4];
    const float* proj_w = (const float*)d_in[5];
    const float* proj_b = (const float*)d_in[6];
    const float* ln2_g = (const float*)d_in[7];
    const float* ln2_b = (const float*)d_in[8];
    const float* fc1_w = (const float*)d_in[9];
    const float* fc1_b = (const float*)d_in[10];
    const float* fc2_w = (const float*)d_in[11];
    const float* fc2_b = (const float*)d_in[12];
    float* out = (float*)d_out;

    char* ws = (char*)d_ws;
    U16* hbuf = (U16*)ws;                               // 32768*512 bf16
    U16* big = (U16*)(ws + 33554432);                   // 32768*2048 bf16 max
    U16* wt_qkv = (U16*)(ws + 33554432 + 134217728);    // 1536*512
    U16* wt_proj = wt_qkv + 1536 * 512;                 // 512*512
    U16* wt_fc1 = wt_proj + 512 * 512;                  // 2048*512
    U16* wt_fc2 = wt_fc1 + 2048 * 512;                  // 512*2048

    dim3 tb(32, 8);
    tcast_kernel<<<dim3(1536 / 32, 512 / 32), tb, 0, stream>>>(qkv_w, wt_qkv, 512, 1536);
    tcast_kernel<<<dim3(512 / 32, 512 / 32), tb, 0, stream>>>(proj_w, wt_proj, 512, 512);
    tcast_kernel<<<dim3(2048 / 32, 512 / 32), tb, 0, stream>>>(fc1_w, wt_fc1, 512, 2048);
    tcast_kernel<<<dim3(512 / 32, 2048 / 32), tb, 0, stream>>>(fc2_w, wt_fc2, 2048, 512);

    ln_kernel<<<8192, 256, 0, stream>>>(x, ln1_g, ln1_b, hbuf);
    gemm_rt<0, 512><<<3072, 256, 0, stream>>>(hbuf, wt_qkv, qkv_b, nullptr, big, nullptr, 32768, 1536, 12);
    attn_kernel<<<4096, 256, 0, stream>>>(big, hbuf);
    gemm_rt<1, 512><<<1024, 256, 0, stream>>>(hbuf, wt_proj, proj_b, x, nullptr, out, 32768, 512, 4);
    ln_kernel<<<8192, 256, 0, stream>>>(out, ln2_g, ln2_b, hbuf);
    gemm_rt<2, 512><<<4096, 256, 0, stream>>>(hbuf, wt_fc1, fc1_b, nullptr, big, nullptr, 32768, 2048, 16);
    gemm_rt<1, 2048><<<1024, 256, 0, stream>>>(big, wt_fc2, fc2_b, out, nullptr, out, 32768, 512, 4);
}